// Round 4
// baseline (1033.238 us; speedup 1.0000x reference)
//
#include <hip/hip_runtime.h>
#include <hip/hip_bf16.h>
#include <stdint.h>
#include <math.h>

typedef float  f32x4 __attribute__((ext_vector_type(4)));
typedef short  s16x8 __attribute__((ext_vector_type(8)));

#define BEPS 1e-5f

typedef const void __attribute__((address_space(1))) gvoid_t;
typedef void       __attribute__((address_space(3))) lvoid_t;

__device__ __forceinline__ void gload_lds16(const void* g, void* l) {
  __builtin_amdgcn_global_load_lds((gvoid_t*)g, (lvoid_t*)l, 16, 0, 0);
}

// ---------------- sign conversion: fp32 -> bf16 (+1.0 / -1.0 bit patterns) -------------
// thresh = -1/256 for quantize8+sign composite (layer-1 input), 0.0 for weights.
__global__ void k_sign(const float* __restrict__ in, ushort* __restrict__ out,
                       long n4, float thresh) {
  const long stride = (long)gridDim.x * blockDim.x;
  for (long i = (long)blockIdx.x * blockDim.x + threadIdx.x; i < n4; i += stride) {
    float4 v = reinterpret_cast<const float4*>(in)[i];
    ushort4 o;
    o.x = (v.x >= thresh) ? (ushort)0x3F80u : (ushort)0xBF80u;
    o.y = (v.y >= thresh) ? (ushort)0x3F80u : (ushort)0xBF80u;
    o.z = (v.z >= thresh) ? (ushort)0x3F80u : (ushort)0xBF80u;
    o.w = (v.w >= thresh) ? (ushort)0x3F80u : (ushort)0xBF80u;
    reinterpret_cast<ushort4*>(out)[i] = o;
  }
}

// W3 (1000 x 4096) -> padded (1024 x 4096), pad rows = +1
__global__ void k_sign_w3(const float* __restrict__ in, ushort* __restrict__ out) {
  const long n4 = 1024L * 1024;  // 1024*4096/4
  const long stride = (long)gridDim.x * blockDim.x;
  for (long i = (long)blockIdx.x * blockDim.x + threadIdx.x; i < n4; i += stride) {
    long row = i >> 10;  // /(4096/4)
    ushort4 o;
    if (row < 1000) {
      float4 v = reinterpret_cast<const float4*>(in)[i];
      o.x = (v.x >= 0.f) ? (ushort)0x3F80u : (ushort)0xBF80u;
      o.y = (v.y >= 0.f) ? (ushort)0x3F80u : (ushort)0xBF80u;
      o.z = (v.z >= 0.f) ? (ushort)0x3F80u : (ushort)0xBF80u;
      o.w = (v.w >= 0.f) ? (ushort)0x3F80u : (ushort)0xBF80u;
    } else {
      o.x = o.y = o.z = o.w = (ushort)0x3F80u;
    }
    reinterpret_cast<ushort4*>(out)[i] = o;
  }
}

// ---------------- fused binary GEMM (NT, bf16 MFMA) + BN epilogue --------------------
// C[m][n] = sum_k A[m][k]*B[n][k]; then h = ((C + bias) - mean)*(g/sqrt(v+eps)) + beta
// EPI==0: write sign(h) as bf16 ushort (activation for next layer)
// EPI==1: write h as fp32 to output, only cols < Nreal, row stride ldC
// Grid MUST be divisible by 8 (XCD swizzle is exact-bijective only then).
template<int EPI>
__global__ __launch_bounds__(256, 2)
void k_gemm_bt(const ushort* __restrict__ A,   // M x K  bf16 bits
               const ushort* __restrict__ B,   // Npad x K bf16 bits
               void* __restrict__ Cout,
               const float* __restrict__ bias, const float* __restrict__ gam,
               const float* __restrict__ bet,  const float* __restrict__ mean,
               const float* __restrict__ var,
               int M, int Npad, int K, int Nreal, int ldC)
{
  __shared__ ushort As[128 * 32];
  __shared__ ushort Bs[128 * 32];

  const int tid  = threadIdx.x;
  const int lane = tid & 63;
  const int wave = tid >> 6;
  const int wr   = wave >> 1;     // wave row (0..1)  -> 64 output rows
  const int wc   = wave & 1;      // wave col (0..1)  -> 64 output cols
  const int fr   = lane & 15;
  const int fq   = lane >> 4;

  // T1: XCD-aware bijective swizzle. Blocks b with b%8==x all dispatch to XCD x;
  // remap so each XCD owns a contiguous chunk of tiles (shared A panels -> L2 hits).
  const int nwg = (int)gridDim.x;           // divisible by 8 by construction
  const int q   = nwg >> 3;
  const int bid = (int)blockIdx.x;
  const int swz = (bid & 7) * q + (bid >> 3);

  const int  nTN = Npad >> 7;
  const int  tm  = swz / nTN;
  const int  tn  = swz % nTN;
  const long m0  = (long)tm * 128;
  const long n0  = (long)tn * 128;

  f32x4 acc[4][4];
#pragma unroll
  for (int i = 0; i < 4; ++i)
#pragma unroll
    for (int j = 0; j < 4; ++j) acc[i][j] = (f32x4){0.f, 0.f, 0.f, 0.f};

  // staging: tile = 128 rows x 64B; 512 chunks of 16B; thread handles chunks c0,c1
  const int c0 = wave * 64 + lane;
  const int c1 = c0 + 256;
  const ushort* Ag0 = A + (m0 + (c0 >> 2)) * K + (c0 & 3) * 8;
  const ushort* Ag1 = A + (m0 + (c1 >> 2)) * K + (c1 & 3) * 8;
  const ushort* Bg0 = B + (n0 + (c0 >> 2)) * K + (c0 & 3) * 8;
  const ushort* Bg1 = B + (n0 + (c1 >> 2)) * K + (c1 & 3) * 8;
  ushort* AsP0 = As + c0 * 8;
  ushort* AsP1 = As + c1 * 8;
  ushort* BsP0 = Bs + c0 * 8;
  ushort* BsP1 = Bs + c1 * 8;

  // fragment read bases: row-major [128][32] bf16 tiles
  const ushort* aRd = As + (wr * 64 + fr) * 32 + fq * 8;
  const ushort* bRd = Bs + (wc * 64 + fr) * 32 + fq * 8;

  const int KSTEPS = K >> 5;
  for (int ks = 0; ks < KSTEPS; ++ks) {
    gload_lds16(Ag0, AsP0);
    gload_lds16(Ag1, AsP1);
    gload_lds16(Bg0, BsP0);
    gload_lds16(Bg1, BsP1);
    Ag0 += 32; Ag1 += 32; Bg0 += 32; Bg1 += 32;
    __syncthreads();   // compiler emits s_waitcnt vmcnt(0) before s_barrier

    s16x8 aF[4], bF[4];
#pragma unroll
    for (int i = 0; i < 4; ++i) aF[i] = *(const s16x8*)(aRd + i * 16 * 32);
#pragma unroll
    for (int j = 0; j < 4; ++j) bF[j] = *(const s16x8*)(bRd + j * 16 * 32);
#pragma unroll
    for (int i = 0; i < 4; ++i)
#pragma unroll
      for (int j = 0; j < 4; ++j)
        acc[i][j] = __builtin_amdgcn_mfma_f32_16x16x32_bf16(aF[i], bF[j], acc[i][j], 0, 0, 0);
    __syncthreads();
  }

  // epilogue: C/D layout (verified): col = lane&15, row = (lane>>4)*4 + reg
  if (EPI == 0) {
    ushort* O = (ushort*)Cout;
#pragma unroll
    for (int j = 0; j < 4; ++j) {
      const long gn = n0 + wc * 64 + j * 16 + fr;
      const float bb  = bias[gn];
      const float mm  = mean[gn];
      const float be_ = bet[gn];
      const float s   = gam[gn] / sqrtf(var[gn] + BEPS);
#pragma unroll
      for (int i = 0; i < 4; ++i) {
#pragma unroll
        for (int r = 0; r < 4; ++r) {
          const long gm = m0 + wr * 64 + i * 16 + fq * 4 + r;
          float h = (acc[i][j][r] + bb - mm) * s + be_;
          O[gm * (long)ldC + gn] = (h >= 0.f) ? (ushort)0x3F80u : (ushort)0xBF80u;
        }
      }
    }
  } else {
    float* O = (float*)Cout;
#pragma unroll
    for (int j = 0; j < 4; ++j) {
      const long gn = n0 + wc * 64 + j * 16 + fr;
      if (gn < Nreal) {
        const float bb  = bias[gn];
        const float mm  = mean[gn];
        const float be_ = bet[gn];
        const float s   = gam[gn] / sqrtf(var[gn] + BEPS);
#pragma unroll
        for (int i = 0; i < 4; ++i) {
#pragma unroll
          for (int r = 0; r < 4; ++r) {
            const long gm = m0 + wr * 64 + i * 16 + fq * 4 + r;
            float h = (acc[i][j][r] + bb - mm) * s + be_;
            O[gm * (long)ldC + gn] = h;
          }
        }
      }
    }
  }
}

extern "C" void kernel_launch(void* const* d_in, const int* in_sizes, int n_in,
                              void* d_out, int out_size, void* d_ws, size_t ws_size,
                              hipStream_t stream) {
  const float* x   = (const float*)d_in[0];
  const float* W1  = (const float*)d_in[1];
  const float* b1  = (const float*)d_in[2];
  const float* g1  = (const float*)d_in[3];
  const float* be1 = (const float*)d_in[4];
  const float* m1  = (const float*)d_in[5];
  const float* v1  = (const float*)d_in[6];
  const float* W2  = (const float*)d_in[7];
  const float* b2  = (const float*)d_in[8];
  const float* g2  = (const float*)d_in[9];
  const float* be2 = (const float*)d_in[10];
  const float* m2  = (const float*)d_in[11];
  const float* v2  = (const float*)d_in[12];
  const float* W3  = (const float*)d_in[13];
  const float* b3  = (const float*)d_in[14];
  const float* g3  = (const float*)d_in[15];
  const float* be3 = (const float*)d_in[16];
  const float* m3  = (const float*)d_in[17];
  const float* v3  = (const float*)d_in[18];
  float* out = (float*)d_out;

  char* ws = (char*)d_ws;
  ushort* ActA = (ushort*)ws;                                 // 8192*4096 bf16 = 64 MB
  ushort* ActB = (ushort*)(ws + 67108864L);                   // 64 MB
  ushort* Wbuf = (ushort*)(ws + 2L * 67108864L);              // 32 MB (W3 uses 8 MB)

  const long n4_x = 8192L * 4096 / 4;
  const long n4_w = 4096L * 4096 / 4;

  // layer-1 input: sign(quantize8(x)) == (x >= -1/256 ? +1 : -1)
  k_sign<<<2048, 256, 0, stream>>>(x, ActA, n4_x, -0.00390625f);
  k_sign<<<2048, 256, 0, stream>>>(W1, Wbuf, n4_w, 0.0f);
  k_gemm_bt<0><<<64 * 32, 256, 0, stream>>>(ActA, Wbuf, ActB, b1, g1, be1, m1, v1,
                                            8192, 4096, 4096, 4096, 4096);
  k_sign<<<2048, 256, 0, stream>>>(W2, Wbuf, n4_w, 0.0f);
  k_gemm_bt<0><<<64 * 32, 256, 0, stream>>>(ActB, Wbuf, ActA, b2, g2, be2, m2, v2,
                                            8192, 4096, 4096, 4096, 4096);
  k_sign_w3<<<1024, 256, 0, stream>>>(W3, Wbuf);
  k_gemm_bt<1><<<64 * 8, 256, 0, stream>>>(ActA, Wbuf, out, b3, g3, be3, m3, v3,
                                           8192, 1024, 4096, 1000, 1000);
}

// Round 7
// 839.329 us; speedup vs baseline: 1.2310x; 1.2310x over previous
//
#include <hip/hip_runtime.h>
#include <hip/hip_bf16.h>
#include <stdint.h>
#include <math.h>

typedef float  f32x4 __attribute__((ext_vector_type(4)));
typedef short  s16x8 __attribute__((ext_vector_type(8)));

#define BEPS 1e-5f

typedef const void __attribute__((address_space(1))) gvoid_t;
typedef void       __attribute__((address_space(3))) lvoid_t;

__device__ __forceinline__ void gload_lds16(const void* g, void* l) {
  __builtin_amdgcn_global_load_lds((gvoid_t*)g, (lvoid_t*)l, 16, 0, 0);
}

// ---------------- sign conversion: fp32 -> bf16 (+1.0 / -1.0 bit patterns) -------------
__global__ void k_sign(const float* __restrict__ in, ushort* __restrict__ out,
                       long n4, float thresh) {
  const long stride = (long)gridDim.x * blockDim.x;
  for (long i = (long)blockIdx.x * blockDim.x + threadIdx.x; i < n4; i += stride) {
    float4 v = reinterpret_cast<const float4*>(in)[i];
    ushort4 o;
    o.x = (v.x >= thresh) ? (ushort)0x3F80u : (ushort)0xBF80u;
    o.y = (v.y >= thresh) ? (ushort)0x3F80u : (ushort)0xBF80u;
    o.z = (v.z >= thresh) ? (ushort)0x3F80u : (ushort)0xBF80u;
    o.w = (v.w >= thresh) ? (ushort)0x3F80u : (ushort)0xBF80u;
    reinterpret_cast<ushort4*>(out)[i] = o;
  }
}

// W3 (1000 x 4096) -> padded (1024 x 4096), pad rows = +1
__global__ void k_sign_w3(const float* __restrict__ in, ushort* __restrict__ out) {
  const long n4 = 1024L * 1024;
  const long stride = (long)gridDim.x * blockDim.x;
  for (long i = (long)blockIdx.x * blockDim.x + threadIdx.x; i < n4; i += stride) {
    long row = i >> 10;
    ushort4 o;
    if (row < 1000) {
      float4 v = reinterpret_cast<const float4*>(in)[i];
      o.x = (v.x >= 0.f) ? (ushort)0x3F80u : (ushort)0xBF80u;
      o.y = (v.y >= 0.f) ? (ushort)0x3F80u : (ushort)0xBF80u;
      o.z = (v.z >= 0.f) ? (ushort)0x3F80u : (ushort)0xBF80u;
      o.w = (v.w >= 0.f) ? (ushort)0x3F80u : (ushort)0xBF80u;
    } else {
      o.x = o.y = o.z = o.w = (ushort)0x3F80u;
    }
    reinterpret_cast<ushort4*>(out)[i] = o;
  }
}

// =====================================================================================
// 256x256 8-wave deep-pipelined binary GEMM (NT, bf16 MFMA) + fused BN + sign epilogue.
// 4 phases/K-tile, counted vmcnt(4) once per K-tile (never 0 in main loop),
// T2 swizzle (involution chunk^=(row&7), LDS dest linear / global source pre-swizzled),
// T5 setprio around MFMA clusters. A staged 1 tile ahead, B 2 tiles ahead;
// tail: A(NK-1) staged explicitly after the main loop (it falls outside the
// loop's A(kt+1) window — missing it reads stale A for the last K-tile).
// =====================================================================================
#define MF(a, b, c) __builtin_amdgcn_mfma_f32_16x16x32_bf16(a, b, c, 0, 0, 0)
#define PH_MFMA(i0, i1) \
  acc[i0][0]=MF(x0,b0k0,acc[i0][0]); acc[i0][0]=MF(x1,b0k1,acc[i0][0]); \
  acc[i0][1]=MF(x0,b1k0,acc[i0][1]); acc[i0][1]=MF(x1,b1k1,acc[i0][1]); \
  acc[i0][2]=MF(x0,b2k0,acc[i0][2]); acc[i0][2]=MF(x1,b2k1,acc[i0][2]); \
  acc[i0][3]=MF(x0,b3k0,acc[i0][3]); acc[i0][3]=MF(x1,b3k1,acc[i0][3]); \
  acc[i1][0]=MF(y0,b0k0,acc[i1][0]); acc[i1][0]=MF(y1,b0k1,acc[i1][0]); \
  acc[i1][1]=MF(y0,b1k0,acc[i1][1]); acc[i1][1]=MF(y1,b1k1,acc[i1][1]); \
  acc[i1][2]=MF(y0,b2k0,acc[i1][2]); acc[i1][2]=MF(y1,b2k1,acc[i1][2]); \
  acc[i1][3]=MF(y0,b3k0,acc[i1][3]); acc[i1][3]=MF(y1,b3k1,acc[i1][3]);

#define STG_A0(ko, bo) do { gload_lds16(Ag00 + (ko), &lds[(bo) + dst0]); \
                            gload_lds16(Ag01 + (ko), &lds[(bo) + dst1]); } while (0)
#define STG_A1(ko, bo) do { gload_lds16(Ag10 + (ko), &lds[(bo) + 8192 + dst0]); \
                            gload_lds16(Ag11 + (ko), &lds[(bo) + 8192 + dst1]); } while (0)
#define STG_B0(ko, bo) do { gload_lds16(Bg00 + (ko), &lds[(bo) + 16384 + dst0]); \
                            gload_lds16(Bg01 + (ko), &lds[(bo) + 16384 + dst1]); } while (0)
#define STG_B1(ko, bo) do { gload_lds16(Bg10 + (ko), &lds[(bo) + 24576 + dst0]); \
                            gload_lds16(Bg11 + (ko), &lds[(bo) + 24576 + dst1]); } while (0)

#define RA(bo, i, k) (*(const s16x8*)&lds[(bo) + aBase + (i) * 1024 + (k)])
#define RB(bo, j, k) (*(const s16x8*)&lds[(bo) + bBase + (j) * 1024 + (k)])

__global__ __launch_bounds__(512, 2)
void k_gemm256(const ushort* __restrict__ A,   // M x K  bf16 bits
               const ushort* __restrict__ B,   // Npad x K bf16 bits
               ushort* __restrict__ Cout,      // M x Npad sign-bf16
               const float* __restrict__ bias, const float* __restrict__ gam,
               const float* __restrict__ bet,  const float* __restrict__ mean,
               const float* __restrict__ var,
               int M, int Npad, int K)
{
  extern __shared__ ushort lds[];   // [2 buf][A 16384 | B 16384] = 131072 B

  const int tid  = threadIdx.x;
  const int lane = tid & 63;
  const int wave = tid >> 6;
  const int wr   = wave >> 2;       // 0..1: 128-row M block
  const int wc   = wave & 3;        // 0..3: 64-col  N block
  const int fr   = lane & 15;
  const int fq   = lane >> 4;

  // XCD-aware bijective swizzle (grid divisible by 8)
  const int nwg = (int)gridDim.x;
  const int q8  = nwg >> 3;
  const int bid = (int)blockIdx.x;
  const int swzb = (bid & 7) * q8 + (bid >> 3);
  const int nTN = Npad >> 8;
  const long m0 = (long)(swzb / nTN) * 256;
  const long n0 = (long)(swzb % nTN) * 256;

  // ---- staging: LDS dest linear, global source pre-swizzled (same involution as read)
  const int colS = ((tid & 7) * 8) ^ (((tid >> 3) & 7) << 3);   // elements within K-tile
  const int r0   = tid >> 3;                                    // row-in-half
  const int dst0 = tid * 8;
  const int dst1 = (tid + 512) * 8;
  const ushort* Ag00 = A + (m0 +       r0     ) * (long)K + colS;
  const ushort* Ag01 = A + (m0 +       r0 + 64) * (long)K + colS;
  const ushort* Ag10 = A + (m0 + 128 + r0     ) * (long)K + colS;
  const ushort* Ag11 = A + (m0 + 128 + r0 + 64) * (long)K + colS;
  const ushort* Bg00 = B + (n0 +       r0     ) * (long)K + colS;
  const ushort* Bg01 = B + (n0 +       r0 + 64) * (long)K + colS;
  const ushort* Bg10 = B + (n0 + 128 + r0     ) * (long)K + colS;
  const ushort* Bg11 = B + (n0 + 128 + r0 + 64) * (long)K + colS;

  // ---- fragment read bases (element offsets into lds), swizzle = XOR ((fr&7)<<3)
  const int ce0   = (fq * 8) ^ ((fr & 7) << 3);
  const int ce1   = ce0 ^ 32;
  const int aBase = wr * 8192 + fr * 64;
  const int bBase = 16384 + (wc >> 1) * 8192 + (wc & 1) * 4096 + fr * 64;

  f32x4 acc[8][4];
#pragma unroll
  for (int i = 0; i < 8; ++i)
#pragma unroll
    for (int j = 0; j < 4; ++j) acc[i][j] = (f32x4){0.f, 0.f, 0.f, 0.f};

  // ---- prologue: stage K-tiles 0 (buf0) and 1 (buf1); issue order fixed for vmcnt math
  STG_A0(0, 0);      STG_A1(0, 0);      STG_B0(0, 0);      STG_B1(0, 0);
  STG_A0(64, 32768); STG_A1(64, 32768); STG_B0(64, 32768); STG_B1(64, 32768);

  const int NK = K >> 6;
  for (int kt = 0; kt < NK - 2; ++kt) {
    const int curO = (kt & 1) << 15;
    const int nxtO = curO ^ 32768;
    const int koA  = (kt + 1) << 6;
    const int koB  = (kt + 2) << 6;

    // ---------------- phase 0: gate + B-frags + A{0,1} ----------------
    // steady state outstanding = [B(kt)x4, A(kt)x4, B(kt+1)x4]; vmcnt(4) retires
    // exactly A(kt),B(kt); B(kt+1) stays in flight across the barrier.
    asm volatile("s_waitcnt vmcnt(4)" ::: "memory");
    __builtin_amdgcn_s_barrier();
    __builtin_amdgcn_sched_barrier(0);
    s16x8 b0k0 = RB(curO,0,ce0), b0k1 = RB(curO,0,ce1),
          b1k0 = RB(curO,1,ce0), b1k1 = RB(curO,1,ce1),
          b2k0 = RB(curO,2,ce0), b2k1 = RB(curO,2,ce1),
          b3k0 = RB(curO,3,ce0), b3k1 = RB(curO,3,ce1);
    s16x8 x0 = RA(curO,0,ce0), x1 = RA(curO,0,ce1),
          y0 = RA(curO,1,ce0), y1 = RA(curO,1,ce1);
    if (kt >= 1) STG_A0(koA, nxtO);                    // A slot of nxt dead since prev ph3
    asm volatile("s_waitcnt lgkmcnt(0)" ::: "memory");
    __builtin_amdgcn_sched_barrier(0);
    __builtin_amdgcn_s_setprio(1);
    PH_MFMA(0, 1)
    __builtin_amdgcn_s_setprio(0);
    __builtin_amdgcn_s_barrier();

    // ---------------- phase 1: A{2,3} ----------------
    x0 = RA(curO,2,ce0); x1 = RA(curO,2,ce1);
    y0 = RA(curO,3,ce0); y1 = RA(curO,3,ce1);
    if (kt >= 1) STG_A1(koA, nxtO);
    STG_B0(koB, curO);                                 // B slots of cur dead after phase 0
    asm volatile("s_waitcnt lgkmcnt(0)" ::: "memory");
    __builtin_amdgcn_sched_barrier(0);
    __builtin_amdgcn_s_setprio(1);
    PH_MFMA(2, 3)
    __builtin_amdgcn_s_setprio(0);
    __builtin_amdgcn_s_barrier();

    // ---------------- phase 2: A{4,5} ----------------
    x0 = RA(curO,4,ce0); x1 = RA(curO,4,ce1);
    y0 = RA(curO,5,ce0); y1 = RA(curO,5,ce1);
    STG_B1(koB, curO);
    asm volatile("s_waitcnt lgkmcnt(0)" ::: "memory");
    __builtin_amdgcn_sched_barrier(0);
    __builtin_amdgcn_s_setprio(1);
    PH_MFMA(4, 5)
    __builtin_amdgcn_s_setprio(0);
    __builtin_amdgcn_s_barrier();

    // ---------------- phase 3: A{6,7} ----------------
    x0 = RA(curO,6,ce0); x1 = RA(curO,6,ce1);
    y0 = RA(curO,7,ce0); y1 = RA(curO,7,ce1);
    asm volatile("s_waitcnt lgkmcnt(0)" ::: "memory");
    __builtin_amdgcn_sched_barrier(0);
    __builtin_amdgcn_s_setprio(1);
    PH_MFMA(6, 7)
    __builtin_amdgcn_s_setprio(0);
    __builtin_amdgcn_s_barrier();
  }

  // ---- tail fix: A(NK-1) is outside the loop's A(kt+1) window — stage it now.
  // Its region (buf[(NK-1)&1] A) held A(NK-3), fully read by kt=NK-3's last barrier.
  {
    const int lastO  = ((NK - 1) & 1) << 15;
    const int koLast = (NK - 1) << 6;
    STG_A0(koLast, lastO);
    STG_A1(koLast, lastO);
  }

  // ---- drain once; then peel last 2 K-tiles (everything resident) ----
  asm volatile("s_waitcnt vmcnt(0)" ::: "memory");
  __builtin_amdgcn_s_barrier();
  __builtin_amdgcn_sched_barrier(0);
  for (int kt = NK - 2; kt < NK; ++kt) {
    const int curO = (kt & 1) << 15;
    s16x8 b0k0 = RB(curO,0,ce0), b0k1 = RB(curO,0,ce1),
          b1k0 = RB(curO,1,ce0), b1k1 = RB(curO,1,ce1),
          b2k0 = RB(curO,2,ce0), b2k1 = RB(curO,2,ce1),
          b3k0 = RB(curO,3,ce0), b3k1 = RB(curO,3,ce1);
    s16x8 x0 = RA(curO,0,ce0), x1 = RA(curO,0,ce1),
          y0 = RA(curO,1,ce0), y1 = RA(curO,1,ce1);
    asm volatile("s_waitcnt lgkmcnt(0)" ::: "memory");
    __builtin_amdgcn_sched_barrier(0);
    PH_MFMA(0, 1)
    x0 = RA(curO,2,ce0); x1 = RA(curO,2,ce1);
    y0 = RA(curO,3,ce0); y1 = RA(curO,3,ce1);
    asm volatile("s_waitcnt lgkmcnt(0)" ::: "memory");
    __builtin_amdgcn_sched_barrier(0);
    PH_MFMA(2, 3)
    x0 = RA(curO,4,ce0); x1 = RA(curO,4,ce1);
    y0 = RA(curO,5,ce0); y1 = RA(curO,5,ce1);
    asm volatile("s_waitcnt lgkmcnt(0)" ::: "memory");
    __builtin_amdgcn_sched_barrier(0);
    PH_MFMA(4, 5)
    x0 = RA(curO,6,ce0); x1 = RA(curO,6,ce1);
    y0 = RA(curO,7,ce0); y1 = RA(curO,7,ce1);
    asm volatile("s_waitcnt lgkmcnt(0)" ::: "memory");
    __builtin_amdgcn_sched_barrier(0);
    PH_MFMA(6, 7)
  }

  // ---- epilogue: BN + sign, C/D layout col=lane&15, row=(lane>>4)*4+reg ----
#pragma unroll
  for (int j = 0; j < 4; ++j) {
    const long gn = n0 + wc * 64 + j * 16 + fr;
    const float bb  = bias[gn];
    const float mm  = mean[gn];
    const float be_ = bet[gn];
    const float s   = gam[gn] / sqrtf(var[gn] + BEPS);
#pragma unroll
    for (int i = 0; i < 8; ++i) {
#pragma unroll
      for (int rr = 0; rr < 4; ++rr) {
        const long gm = m0 + wr * 128 + i * 16 + fq * 4 + rr;
        float h = (acc[i][j][rr] + bb - mm) * s + be_;
        Cout[gm * (long)Npad + gn] = (h >= 0.f) ? (ushort)0x3F80u : (ushort)0xBF80u;
      }
    }
  }
}

// ---------------- 128x128 m97-structure GEMM (kept for the N=1024 layer-3) -----------
template<int EPI>
__global__ __launch_bounds__(256, 2)
void k_gemm_bt(const ushort* __restrict__ A, const ushort* __restrict__ B,
               void* __restrict__ Cout,
               const float* __restrict__ bias, const float* __restrict__ gam,
               const float* __restrict__ bet,  const float* __restrict__ mean,
               const float* __restrict__ var,
               int M, int Npad, int K, int Nreal, int ldC)
{
  __shared__ ushort As[128 * 32];
  __shared__ ushort Bs[128 * 32];

  const int tid  = threadIdx.x;
  const int lane = tid & 63;
  const int wave = tid >> 6;
  const int wr   = wave >> 1;
  const int wc   = wave & 1;
  const int fr   = lane & 15;
  const int fq   = lane >> 4;

  const int nwg = (int)gridDim.x;
  const int q   = nwg >> 3;
  const int bid = (int)blockIdx.x;
  const int swz = (bid & 7) * q + (bid >> 3);

  const int  nTN = Npad >> 7;
  const int  tm  = swz / nTN;
  const int  tn  = swz % nTN;
  const long m0  = (long)tm * 128;
  const long n0  = (long)tn * 128;

  f32x4 acc[4][4];
#pragma unroll
  for (int i = 0; i < 4; ++i)
#pragma unroll
    for (int j = 0; j < 4; ++j) acc[i][j] = (f32x4){0.f, 0.f, 0.f, 0.f};

  const int c0 = wave * 64 + lane;
  const int c1 = c0 + 256;
  const ushort* Ag0 = A + (m0 + (c0 >> 2)) * K + (c0 & 3) * 8;
  const ushort* Ag1 = A + (m0 + (c1 >> 2)) * K + (c1 & 3) * 8;
  const ushort* Bg0 = B + (n0 + (c0 >> 2)) * K + (c0 & 3) * 8;
  const ushort* Bg1 = B + (n0 + (c1 >> 2)) * K + (c1 & 3) * 8;
  ushort* AsP0 = As + c0 * 8;
  ushort* AsP1 = As + c1 * 8;
  ushort* BsP0 = Bs + c0 * 8;
  ushort* BsP1 = Bs + c1 * 8;

  const ushort* aRd = As + (wr * 64 + fr) * 32 + fq * 8;
  const ushort* bRd = Bs + (wc * 64 + fr) * 32 + fq * 8;

  const int KSTEPS = K >> 5;
  for (int ks = 0; ks < KSTEPS; ++ks) {
    gload_lds16(Ag0, AsP0);
    gload_lds16(Ag1, AsP1);
    gload_lds16(Bg0, BsP0);
    gload_lds16(Bg1, BsP1);
    Ag0 += 32; Ag1 += 32; Bg0 += 32; Bg1 += 32;
    __syncthreads();

    s16x8 aF[4], bF[4];
#pragma unroll
    for (int i = 0; i < 4; ++i) aF[i] = *(const s16x8*)(aRd + i * 16 * 32);
#pragma unroll
    for (int j = 0; j < 4; ++j) bF[j] = *(const s16x8*)(bRd + j * 16 * 32);
#pragma unroll
    for (int i = 0; i < 4; ++i)
#pragma unroll
      for (int j = 0; j < 4; ++j)
        acc[i][j] = __builtin_amdgcn_mfma_f32_16x16x32_bf16(aF[i], bF[j], acc[i][j], 0, 0, 0);
    __syncthreads();
  }

  if (EPI == 0) {
    ushort* O = (ushort*)Cout;
#pragma unroll
    for (int j = 0; j < 4; ++j) {
      const long gn = n0 + wc * 64 + j * 16 + fr;
      const float bb  = bias[gn];
      const float mm  = mean[gn];
      const float be_ = bet[gn];
      const float s   = gam[gn] / sqrtf(var[gn] + BEPS);
#pragma unroll
      for (int i = 0; i < 4; ++i) {
#pragma unroll
        for (int r = 0; r < 4; ++r) {
          const long gm = m0 + wr * 64 + i * 16 + fq * 4 + r;
          float h = (acc[i][j][r] + bb - mm) * s + be_;
          O[gm * (long)ldC + gn] = (h >= 0.f) ? (ushort)0x3F80u : (ushort)0xBF80u;
        }
      }
    }
  } else {
    float* O = (float*)Cout;
#pragma unroll
    for (int j = 0; j < 4; ++j) {
      const long gn = n0 + wc * 64 + j * 16 + fr;
      if (gn < Nreal) {
        const float bb  = bias[gn];
        const float mm  = mean[gn];
        const float be_ = bet[gn];
        const float s   = gam[gn] / sqrtf(var[gn] + BEPS);
#pragma unroll
        for (int i = 0; i < 4; ++i) {
#pragma unroll
          for (int r = 0; r < 4; ++r) {
            const long gm = m0 + wr * 64 + i * 16 + fq * 4 + r;
            float h = (acc[i][j][r] + bb - mm) * s + be_;
            O[gm * (long)ldC + gn] = h;
          }
        }
      }
    }
  }
}

extern "C" void kernel_launch(void* const* d_in, const int* in_sizes, int n_in,
                              void* d_out, int out_size, void* d_ws, size_t ws_size,
                              hipStream_t stream) {
  const float* x   = (const float*)d_in[0];
  const float* W1  = (const float*)d_in[1];
  const float* b1  = (const float*)d_in[2];
  const float* g1  = (const float*)d_in[3];
  const float* be1 = (const float*)d_in[4];
  const float* m1  = (const float*)d_in[5];
  const float* v1  = (const float*)d_in[6];
  const float* W2  = (const float*)d_in[7];
  const float* b2  = (const float*)d_in[8];
  const float* g2  = (const float*)d_in[9];
  const float* be2 = (const float*)d_in[10];
  const float* m2  = (const float*)d_in[11];
  const float* v2  = (const float*)d_in[12];
  const float* W3  = (const float*)d_in[13];
  const float* b3  = (const float*)d_in[14];
  const float* g3  = (const float*)d_in[15];
  const float* be3 = (const float*)d_in[16];
  const float* m3  = (const float*)d_in[17];
  const float* v3  = (const float*)d_in[18];
  float* out = (float*)d_out;

  char* ws = (char*)d_ws;
  ushort* ActA = (ushort*)ws;                                 // 64 MB
  ushort* ActB = (ushort*)(ws + 67108864L);                   // 64 MB
  ushort* Wbuf = (ushort*)(ws + 2L * 67108864L);              // 32 MB

  const long n4_x = 8192L * 4096 / 4;
  const long n4_w = 4096L * 4096 / 4;

  // layer-1 input: sign(quantize8(x)) == (x >= -1/256 ? +1 : -1)
  k_sign<<<2048, 256, 0, stream>>>(x, ActA, n4_x, -0.00390625f);
  k_sign<<<2048, 256, 0, stream>>>(W1, Wbuf, n4_w, 0.0f);
  k_gemm256<<<512, 512, 131072, stream>>>(ActA, Wbuf, ActB, b1, g1, be1, m1, v1,
                                          8192, 4096, 4096);
  k_sign<<<2048, 256, 0, stream>>>(W2, Wbuf, n4_w, 0.0f);
  k_gemm256<<<512, 512, 131072, stream>>>(ActB, Wbuf, ActA, b2, g2, be2, m2, v2,
                                          8192, 4096, 4096);
  k_sign_w3<<<1024, 256, 0, stream>>>(W3, Wbuf);
  k_gemm_bt<1><<<64 * 8, 256, 0, stream>>>(ActA, Wbuf, out, b3, g3, be3, m3, v3,
                                           8192, 1024, 4096, 1000, 1000);
}